// Round 14
// baseline (112.684 us; speedup 1.0000x reference)
//
#include <hip/hip_runtime.h>
#include <math.h>

#define NN 10000
#define EE 640000
#define DD 256
#define SB 128            // scatter blocks per conv pass; EE/SB = 5000 edges each
#define EPB (EE / SB)
#define FB 64             // finalize/waiter blocks per conv pass
#define NPF 157           // nodes per finalize block: 64*157 = 10048 >= NN
#define NTHR 512
#define RB 157            // K2 reduce blocks (157*64 >= NN)

// ws float-offset layout
#define OFF_DINV 0
#define OFF_XW   (NN)
#define OFF_C1   (2*NN)
#define OFF_C2   (3*NN)
#define OFF_U0   (4*NN)
#define OFF_U1   (5*NN)
#define OFF_U2   (6*NN)
#define OFF_XP   (7*NN)         // [0..143] xp1, [144] regAcc, int ctrs at [146..149]
#define OFF_PART (7*NN + 160)   // SB*NN floats (5.12 MB), reused each pass

#define CTR_A 146               // conv1 scatter-done
#define CTR_B 147               // conv2 scatter-done
#define CTR_C 148               // conv3 scatter-done
#define CTR_D 149               // pool finalize-done

// K1: deg scatter (blocks 0..SB-1: LDS acc, coalesced flush to partials)
//     + xw = x@W1 fused (all 256 blocks). Block 0 zeroes xp1/reg/counters.
__global__ __launch_bounds__(NTHR) void k1_deg_xw(
    const int* __restrict__ dst, const float* __restrict__ ew,
    const float* __restrict__ x, const float* __restrict__ W1,
    float* __restrict__ ws)
{
    __shared__ float acc[NN];    // 40 KB
    int tid = threadIdx.x, bid = blockIdx.x;
    int lane = tid & 63, wv = tid >> 6;
    if (bid == 0 && tid < 160) ws[OFF_XP + tid] = 0.f;   // xp1 + reg + all ctrs
    if (bid < SB) {
        for (int i = tid; i < NN; i += NTHR) acc[i] = 0.f;
    }
    __syncthreads();
    {   // xw: wave per row, float4 dot + butterfly (256 blocks x 8 waves)
        float4 wreg = reinterpret_cast<const float4*>(W1)[lane];
        float* xw = ws + OFF_XW;
        for (int row = bid * 8 + wv; row < NN; row += 256 * 8) {
            float4 a = reinterpret_cast<const float4*>(x + (size_t)row * DD)[lane];
            float v = a.x*wreg.x + a.y*wreg.y + a.z*wreg.z + a.w*wreg.w;
            #pragma unroll
            for (int off = 32; off; off >>= 1) v += __shfl_xor(v, off);
            if (lane == 0) xw[row] = v;
        }
    }
    if (bid < SB) {
        int base = bid * EPB;
        for (int k = tid; k < EPB; k += NTHR) {
            int e = base + k;
            atomicAdd(&acc[dst[e]], ew[e]);
        }
        __syncthreads();
        float* p = ws + OFF_PART + (size_t)bid * NN;
        for (int i = tid; i < NN; i += NTHR) p[i] = acc[i];
    }
}

// K2: reduce deg partials -> dinv = (1+deg)^(-1/2); u0 = dinv*xw.
__global__ __launch_bounds__(NTHR) void k2_dinv(float* __restrict__ ws)
{
    __shared__ float red[8][64];
    int tid = threadIdx.x, bid = blockIdx.x;
    int nl = tid & 63, sl = tid >> 6;
    int node = bid * 64 + nl;
    const float* part = ws + OFF_PART;
    float s = 0.f;
    if (node < NN) {
        #pragma unroll 8
        for (int it = 0; it < SB / 8; ++it)
            s += part[(size_t)(sl * (SB / 8) + it) * NN + node];
    }
    red[sl][nl] = s;
    __syncthreads();
    if (tid < 64 && node < NN) {
        float tot = 1.f;                   // self-loop weight
        #pragma unroll
        for (int q = 0; q < 8; ++q) tot += red[q][tid];
        float di = (tot > 0.f) ? 1.0f / sqrtf(tot) : 0.f;
        ws[OFF_DINV + node] = di;
        ws[OFF_U0 + node] = di * ws[OFF_XW + node];
    }
}

// K3/K4: fused conv pass. Blocks 0..SB-1: LDS scatter of ew*uin[src] by dst,
// flush partials, release-arrive on ctr. Blocks SB..SB+FB-1: spin on ctr,
// acquire, reduce 128 slices for own 157 nodes, finalize c,u.
__global__ __launch_bounds__(NTHR) void k_scat_fin(
    const int* __restrict__ src, const int* __restrict__ dst,
    const float* __restrict__ ew, const float* __restrict__ uin,
    const float* __restrict__ hin, const float* __restrict__ multp,
    const float* __restrict__ biasp, float* __restrict__ cout,
    float* __restrict__ uout, int ctrIdx, float* __restrict__ ws)
{
    __shared__ float acc[NN];          // 40 KB (scatter blocks)
    __shared__ float red[8][NPF];      // ~5 KB  (waiter blocks)
    int tid = threadIdx.x, bid = blockIdx.x;
    int lane = tid & 63, wv = tid >> 6;
    int* ctr = (int*)(ws + OFF_XP) + ctrIdx;
    if (bid < SB) {
        for (int i = tid; i < NN; i += NTHR) acc[i] = 0.f;
        __syncthreads();
        int base = bid * EPB;
        for (int k = tid; k < EPB; k += NTHR) {
            int e = base + k;
            atomicAdd(&acc[dst[e]], ew[e] * uin[src[e]]);
        }
        __syncthreads();
        float* p = ws + OFF_PART + (size_t)bid * NN;
        for (int i = tid; i < NN; i += NTHR) p[i] = acc[i];
        __syncthreads();                 // all stores drained (vmcnt0) pre-arrive
        if (tid == 0)
            __hip_atomic_fetch_add(ctr, 1, __ATOMIC_RELEASE, __HIP_MEMORY_SCOPE_AGENT);
    } else {
        if (tid == 0) {
            while (__hip_atomic_load(ctr, __ATOMIC_RELAXED, __HIP_MEMORY_SCOPE_AGENT) < SB)
                __builtin_amdgcn_s_sleep(2);
            __builtin_amdgcn_fence(__ATOMIC_ACQUIRE, "agent");
        }
        __syncthreads();
        int nbase = (bid - SB) * NPF;
        const float* part = ws + OFF_PART;
        for (int n = lane; n < NPF; n += 64) {
            float s = 0.f;
            if (nbase + n < NN) {
                #pragma unroll
                for (int q = 0; q < 16; ++q)
                    s += part[(size_t)(wv * 16 + q) * NN + nbase + n];
            }
            red[wv][n] = s;
        }
        __syncthreads();
        float M = multp ? *multp : 1.0f;
        float B = *biasp;
        for (int t = tid; t < NPF; t += NTHR) {
            int node = nbase + t;
            if (node < NN) {
                float tot = 0.f;
                #pragma unroll
                for (int q = 0; q < 8; ++q) tot += red[q][t];
                float di = ws[OFF_DINV + node];
                float cv = M * di * (tot + di * hin[node]) + B;
                cout[node] = cv;
                uout[node] = di * cv;
            }
        }
    }
}

// K5: conv3 scatter + waiter finalize c3 (LDS-local) + pool stage 1 over own
//     157 rows + last-of-64 pool stages 2..4 -> out.
__global__ __launch_bounds__(NTHR) void k5_scat_pool(
    const int* __restrict__ src, const int* __restrict__ dst,
    const float* __restrict__ ew, const float* __restrict__ uin,
    const float* __restrict__ hin, const float* __restrict__ multp,
    const float* __restrict__ biasp, const float* __restrict__ c1,
    const float* __restrict__ c2, const float* __restrict__ P1,
    const float* __restrict__ P2, const float* __restrict__ P3,
    float* __restrict__ ws, float* __restrict__ out)
{
    __shared__ float acc[NN];
    __shared__ float red[8][NPF];
    __shared__ float sc3[NPF];
    __shared__ float part[8][48][3];
    __shared__ float entW[8];
    __shared__ int sh_last;
    int tid = threadIdx.x, bid = blockIdx.x;
    int lane = tid & 63, wv = tid >> 6;
    int* ctr  = (int*)(ws + OFF_XP) + CTR_C;
    int* ctrD = (int*)(ws + OFF_XP) + CTR_D;
    if (bid < SB) {
        for (int i = tid; i < NN; i += NTHR) acc[i] = 0.f;
        __syncthreads();
        int base = bid * EPB;
        for (int k = tid; k < EPB; k += NTHR) {
            int e = base + k;
            atomicAdd(&acc[dst[e]], ew[e] * uin[src[e]]);
        }
        __syncthreads();
        float* p = ws + OFF_PART + (size_t)bid * NN;
        for (int i = tid; i < NN; i += NTHR) p[i] = acc[i];
        __syncthreads();
        if (tid == 0)
            __hip_atomic_fetch_add(ctr, 1, __ATOMIC_RELEASE, __HIP_MEMORY_SCOPE_AGENT);
        return;
    }
    // ---- waiter: finalize c3 + pool stage 1 ----
    if (tid == 0) {
        while (__hip_atomic_load(ctr, __ATOMIC_RELAXED, __HIP_MEMORY_SCOPE_AGENT) < SB)
            __builtin_amdgcn_s_sleep(2);
        __builtin_amdgcn_fence(__ATOMIC_ACQUIRE, "agent");
    }
    __syncthreads();
    int nbase = (bid - SB) * NPF;
    const float* partg = ws + OFF_PART;
    for (int n = lane; n < NPF; n += 64) {
        float s = 0.f;
        if (nbase + n < NN) {
            #pragma unroll
            for (int q = 0; q < 16; ++q)
                s += partg[(size_t)(wv * 16 + q) * NN + nbase + n];
        }
        red[wv][n] = s;
    }
    __syncthreads();
    {
        float M = *multp, B = *biasp;
        for (int t = tid; t < NPF; t += NTHR) {
            int node = nbase + t;
            float cv = 0.f;
            if (node < NN) {
                float tot = 0.f;
                #pragma unroll
                for (int q = 0; q < 8; ++q) tot += red[q][t];
                float di = ws[OFF_DINV + node];
                cv = M * di * (tot + di * hin[node]) + B;
            }
            sc3[t] = cv;
        }
    }
    __syncthreads();
    float a0 = 0.f, a1 = 0.f, a2 = 0.f, ent = 0.f;
    for (int r = 0; r < 20; ++r) {
        int l = wv * 20 + r;
        if (l < NPF && nbase + l < NN) {          // wave-uniform
            int row = nbase + l;
            float pv = (lane < 48) ? P1[(size_t)row * 48 + lane] : -1e30f;
            float mx = pv;
            #pragma unroll
            for (int off = 32; off; off >>= 1) mx = fmaxf(mx, __shfl_xor(mx, off));
            float e = (lane < 48) ? expf(pv - mx) : 0.f;
            float sum = e;
            #pragma unroll
            for (int off = 32; off; off >>= 1) sum += __shfl_xor(sum, off);
            float p = e / sum;
            if (lane < 48) {
                ent -= p * logf(p + 1e-12f);
                a0 += p * c1[row];
                a1 += p * c2[row];
                a2 += p * sc3[l];
            }
        }
    }
    #pragma unroll
    for (int off = 32; off; off >>= 1) ent += __shfl_xor(ent, off);
    if (lane == 0) entW[wv] = ent;
    if (lane < 48) { part[wv][lane][0] = a0; part[wv][lane][1] = a1; part[wv][lane][2] = a2; }
    __syncthreads();
    float* xp1 = ws + OFF_XP;
    if (tid < 144) {
        int j = tid / 3, col = tid % 3;
        float sp = 0.f;
        #pragma unroll
        for (int w = 0; w < 8; ++w) sp += part[w][j][col];
        atomicAdd(&xp1[j * 3 + col], sp);
    }
    if (tid == 0) {
        float sp = 0.f;
        #pragma unroll
        for (int w = 0; w < 8; ++w) sp += entW[w];
        atomicAdd(&xp1[144], sp);
    }
    // ---- last-of-64 epilogue: pool stages 2..4 ----
    if (tid == 0) {
        __threadfence();
        int old = atomicAdd(ctrD, 1);
        sh_last = (old == FB - 1) ? 1 : 0;
    }
    __syncthreads();
    if (sh_last) {
        __shared__ float shXp[145];
        __shared__ float S2[48][12], xp2[12][3];
        __shared__ float S3[12][4], xp3[4][3];
        __shared__ float ent2, ent3;
        if (tid < 145) shXp[tid] = atomicAdd(&xp1[tid], 0.0f);  // coherent read
        if (tid == 0) { ent2 = 0.f; ent3 = 0.f; }
        __syncthreads();
        if (tid < 48) {
            float v[12], mx = -1e30f;
            #pragma unroll
            for (int j = 0; j < 12; j++) { v[j] = P2[tid * 12 + j]; mx = fmaxf(mx, v[j]); }
            float sm = 0.f;
            #pragma unroll
            for (int j = 0; j < 12; j++) { v[j] = expf(v[j] - mx); sm += v[j]; }
            float e = 0.f;
            #pragma unroll
            for (int j = 0; j < 12; j++) {
                float p = v[j] / sm; S2[tid][j] = p; e -= p * logf(p + 1e-12f);
            }
            atomicAdd(&ent2, e);
        }
        __syncthreads();
        if (tid < 36) {
            int j = tid / 3, col = tid % 3;
            float sm = 0.f;
            for (int i = 0; i < 48; i++) sm += S2[i][j] * shXp[i * 3 + col];
            xp2[j][col] = sm;
        }
        __syncthreads();
        if (tid < 12) {
            float v[4], mx = -1e30f;
            #pragma unroll
            for (int j = 0; j < 4; j++) { v[j] = P3[tid * 4 + j]; mx = fmaxf(mx, v[j]); }
            float sm = 0.f;
            #pragma unroll
            for (int j = 0; j < 4; j++) { v[j] = expf(v[j] - mx); sm += v[j]; }
            float e = 0.f;
            #pragma unroll
            for (int j = 0; j < 4; j++) {
                float p = v[j] / sm; S3[tid][j] = p; e -= p * logf(p + 1e-12f);
            }
            atomicAdd(&ent3, e);
        }
        __syncthreads();
        if (tid < 12) {
            int j = tid / 3, col = tid % 3;
            float sm = 0.f;
            for (int i = 0; i < 12; i++) sm += S3[i][j] * xp2[i][col];
            xp3[j][col] = sm;
        }
        __syncthreads();
        if (tid == 0) {
            float o0 = 0.f, o1 = 0.f, o2 = 0.f;
            for (int i = 0; i < 4; i++) {
                o0 += xp3[i][0]; o1 += xp3[i][1]; o2 += xp3[i][2];
            }
            // stage-4: width-1 softmax -> p==1, entropy==0 in fp32
            float reg = shXp[144] / (float)NN + ent2 / 48.f + ent3 / 12.f;
            out[0] = o0; out[1] = o1; out[2] = o2; out[3] = reg;
        }
    }
}

extern "C" void kernel_launch(void* const* d_in, const int* in_sizes, int n_in,
                              void* d_out, int out_size, void* d_ws, size_t ws_size,
                              hipStream_t stream) {
    const float* x  = (const float*)d_in[0];
    const int*   ei = (const int*)d_in[1];
    const float* ea = (const float*)d_in[2];
    // d_in[3] = adj — unused by the reference.
    const float* W1 = (const float*)d_in[4];
    const float* b1 = (const float*)d_in[5];
    const float* W2 = (const float*)d_in[6];
    const float* b2 = (const float*)d_in[7];
    const float* P1 = (const float*)d_in[8];
    const float* P2 = (const float*)d_in[9];
    const float* P3 = (const float*)d_in[10];
    // d_in[11] = P4 — width-1 softmax, handled analytically.
    const int* src = ei;
    const int* dst = ei + EE;
    float* ws  = (float*)d_ws;
    float* out = (float*)d_out;

    k1_deg_xw<<<256, NTHR, 0, stream>>>(dst, ea, x, W1, ws);
    k2_dinv<<<RB, NTHR, 0, stream>>>(ws);
    k_scat_fin<<<SB + FB, NTHR, 0, stream>>>(src, dst, ea, ws + OFF_U0,
                                             ws + OFF_XW, nullptr, b1,
                                             ws + OFF_C1, ws + OFF_U1, CTR_A, ws);
    k_scat_fin<<<SB + FB, NTHR, 0, stream>>>(src, dst, ea, ws + OFF_U1,
                                             ws + OFF_C1, W2, b2,
                                             ws + OFF_C2, ws + OFF_U2, CTR_B, ws);
    k5_scat_pool<<<SB + FB, NTHR, 0, stream>>>(src, dst, ea, ws + OFF_U2,
                                               ws + OFF_C2, W2, b2,
                                               ws + OFF_C1, ws + OFF_C2,
                                               P1, P2, P3, ws, out);
}

// Round 15
// 79.013 us; speedup vs baseline: 1.4261x; 1.4261x over previous
//
#include <hip/hip_runtime.h>
#include <math.h>

#define NN 10000
#define EE 640000
#define DD 256
#define SB 128            // scatter blocks per edge pass; EE/SB = 5000 edges each
#define EPB (EE / SB)     // 5000 (divisible by 4 -> int4/float4 views align)
#define EV4 (EPB / 4)     // 1250 vec4 groups per block
#define NTHR 512
#define RB 157            // reduce blocks: 157*64 = 10048 >= NN

// ws float-offset layout
#define OFF_DINV 0
#define OFF_XW   (NN)
#define OFF_C1   (2*NN)
#define OFF_C2   (3*NN)
#define OFF_U0   (4*NN)
#define OFF_U1   (5*NN)
#define OFF_U2   (6*NN)
#define OFF_XP   (7*NN)         // [0..143] xp1, [144] regAcc, int done-ctr at [152]
#define OFF_PART (7*NN + 160)   // SB*NN floats (5.12 MB), reused each pass

// K1: deg scatter (blocks 0..SB-1: LDS acc, vec4 edge loads, vec4 flush)
//     + xw = x@W1 fused (all 256 blocks, wave per row).
__global__ __launch_bounds__(NTHR) void k1_deg_xw(
    const int* __restrict__ dst, const float* __restrict__ ew,
    const float* __restrict__ x, const float* __restrict__ W1,
    float* __restrict__ ws)
{
    __shared__ float acc[NN];    // 40 KB
    int tid = threadIdx.x, bid = blockIdx.x;
    int lane = tid & 63, wv = tid >> 6;
    if (bid == 0 && tid < 160) ws[OFF_XP + tid] = 0.f;   // xp1 + reg + done-ctr
    if (bid < SB) {
        float4* acc4 = reinterpret_cast<float4*>(acc);
        for (int i = tid; i < NN / 4; i += NTHR) acc4[i] = make_float4(0.f, 0.f, 0.f, 0.f);
    }
    __syncthreads();
    {   // xw: wave per row, float4 dot + butterfly (256 blocks x 8 waves)
        float4 wreg = reinterpret_cast<const float4*>(W1)[lane];
        float* xw = ws + OFF_XW;
        for (int row = bid * 8 + wv; row < NN; row += 256 * 8) {
            float4 a = reinterpret_cast<const float4*>(x + (size_t)row * DD)[lane];
            float v = a.x*wreg.x + a.y*wreg.y + a.z*wreg.z + a.w*wreg.w;
            #pragma unroll
            for (int off = 32; off; off >>= 1) v += __shfl_xor(v, off);
            if (lane == 0) xw[row] = v;
        }
    }
    if (bid < SB) {
        const int4*   d4 = reinterpret_cast<const int4*>(dst + bid * EPB);
        const float4* w4 = reinterpret_cast<const float4*>(ew + bid * EPB);
        for (int v = tid; v < EV4; v += NTHR) {
            int4 d = d4[v]; float4 w = w4[v];
            atomicAdd(&acc[d.x], w.x);
            atomicAdd(&acc[d.y], w.y);
            atomicAdd(&acc[d.z], w.z);
            atomicAdd(&acc[d.w], w.w);
        }
        __syncthreads();
        float4* p4 = reinterpret_cast<float4*>(ws + OFF_PART + (size_t)bid * NN);
        const float4* acc4 = reinterpret_cast<const float4*>(acc);
        for (int i = tid; i < NN / 4; i += NTHR) p4[i] = acc4[i];
    }
}

// K2: reduce deg partials -> dinv = (1+deg)^(-1/2); u0 = dinv*xw.
__global__ __launch_bounds__(NTHR) void k2_dinv(float* __restrict__ ws)
{
    __shared__ float red[8][64];
    int tid = threadIdx.x, bid = blockIdx.x;
    int nl = tid & 63, sl = tid >> 6;
    int node = bid * 64 + nl;
    const float* part = ws + OFF_PART;
    float s = 0.f;
    if (node < NN) {
        #pragma unroll 8
        for (int it = 0; it < SB / 8; ++it)
            s += part[(size_t)(sl * (SB / 8) + it) * NN + node];
    }
    red[sl][nl] = s;
    __syncthreads();
    if (tid < 64 && node < NN) {
        float tot = 1.f;                   // self-loop weight
        #pragma unroll
        for (int q = 0; q < 8; ++q) tot += red[q][tid];
        float di = (tot > 0.f) ? 1.0f / sqrtf(tot) : 0.f;
        ws[OFF_DINV + node] = di;
        ws[OFF_U0 + node] = di * ws[OFF_XW + node];
    }
}

// K3/K5/K7: edge scatter of ew[e]*u[src[e]] into LDS by dst; vec4 loads so 4
// independent u-gathers are in flight per iteration; vec4 flush.
__global__ __launch_bounds__(NTHR) void k_scat(
    const int* __restrict__ src, const int* __restrict__ dst,
    const float* __restrict__ ew, const float* __restrict__ u,
    float* __restrict__ ws)
{
    __shared__ float acc[NN];
    int tid = threadIdx.x, bid = blockIdx.x;
    {
        float4* acc4 = reinterpret_cast<float4*>(acc);
        for (int i = tid; i < NN / 4; i += NTHR) acc4[i] = make_float4(0.f, 0.f, 0.f, 0.f);
    }
    __syncthreads();
    const int4*   s4 = reinterpret_cast<const int4*>(src + bid * EPB);
    const int4*   d4 = reinterpret_cast<const int4*>(dst + bid * EPB);
    const float4* w4 = reinterpret_cast<const float4*>(ew + bid * EPB);
    for (int v = tid; v < EV4; v += NTHR) {
        int4 sv = s4[v]; int4 dv = d4[v]; float4 wv4 = w4[v];
        float ux = u[sv.x], uy = u[sv.y], uz = u[sv.z], uw = u[sv.w];
        atomicAdd(&acc[dv.x], wv4.x * ux);
        atomicAdd(&acc[dv.y], wv4.y * uy);
        atomicAdd(&acc[dv.z], wv4.z * uz);
        atomicAdd(&acc[dv.w], wv4.w * uw);
    }
    __syncthreads();
    float4* p4 = reinterpret_cast<float4*>(ws + OFF_PART + (size_t)bid * NN);
    const float4* acc4 = reinterpret_cast<const float4*>(acc);
    for (int i = tid; i < NN / 4; i += NTHR) p4[i] = acc4[i];
}

// K4/K6: reduce conv partials: c = M*di*(sum + di*hin) + B ; u = di*c.
__global__ __launch_bounds__(NTHR) void k_red_conv(
    const float* __restrict__ hin, const float* __restrict__ multp,
    const float* __restrict__ biasp, float* __restrict__ cout,
    float* __restrict__ uout, float* __restrict__ ws)
{
    __shared__ float red[8][64];
    int tid = threadIdx.x, bid = blockIdx.x;
    int nl = tid & 63, sl = tid >> 6;
    int node = bid * 64 + nl;
    const float* part = ws + OFF_PART;
    float s = 0.f;
    if (node < NN) {
        #pragma unroll 8
        for (int it = 0; it < SB / 8; ++it)
            s += part[(size_t)(sl * (SB / 8) + it) * NN + node];
    }
    red[sl][nl] = s;
    __syncthreads();
    if (tid < 64 && node < NN) {
        float tot = 0.f;
        #pragma unroll
        for (int q = 0; q < 8; ++q) tot += red[q][tid];
        float di = ws[OFF_DINV + node];
        float M = multp ? *multp : 1.0f;
        float cv = M * di * (tot + di * hin[node]) + *biasp;
        cout[node] = cv;
        uout[node] = di * cv;
    }
}

// K8: reduce -> c3 (block-local), pool stage 1 for the block's 64 rows,
//     last-done block runs pool stages 2..4 and writes out.
__global__ __launch_bounds__(NTHR) void k8_final(
    const float* __restrict__ hin,                         // c2
    const float* __restrict__ multp, const float* __restrict__ biasp,
    const float* __restrict__ c1, const float* __restrict__ c2,
    const float* __restrict__ P1, const float* __restrict__ P2,
    const float* __restrict__ P3, float* __restrict__ ws, float* __restrict__ out)
{
    __shared__ float red[8][64];
    __shared__ float s_c3[64];
    __shared__ float part[8][48][3];
    __shared__ float entW[8];
    __shared__ int sh_last;
    int tid = threadIdx.x, bid = blockIdx.x;
    int lane = tid & 63, wv = tid >> 6;
    int node = bid * 64 + lane;
    const float* partg = ws + OFF_PART;
    float s = 0.f;
    if (node < NN) {
        #pragma unroll 8
        for (int it = 0; it < SB / 8; ++it)
            s += partg[(size_t)(wv * (SB / 8) + it) * NN + node];
    }
    red[wv][lane] = s;
    __syncthreads();
    if (tid < 64) {
        float cv = 0.f;
        if (node < NN) {
            float tot = 0.f;
            #pragma unroll
            for (int q = 0; q < 8; ++q) tot += red[q][tid];
            float di = ws[OFF_DINV + node];
            cv = (*multp) * di * (tot + di * hin[node]) + *biasp;
        }
        s_c3[tid] = cv;
    }
    __syncthreads();
    // ---- pool stage 1 over this block's rows: wave wv -> rows wv*8..wv*8+7 ----
    float a0 = 0.f, a1 = 0.f, a2 = 0.f, ent = 0.f;
    for (int j = 0; j < 8; ++j) {
        int rl = wv * 8 + j;
        int row = bid * 64 + rl;
        if (row >= NN) break;                        // wave-uniform
        float v = (lane < 48) ? P1[(size_t)row * 48 + lane] : -1e30f;
        float mx = v;
        #pragma unroll
        for (int off = 32; off; off >>= 1) mx = fmaxf(mx, __shfl_xor(mx, off));
        float e = (lane < 48) ? expf(v - mx) : 0.f;
        float sum = e;
        #pragma unroll
        for (int off = 32; off; off >>= 1) sum += __shfl_xor(sum, off);
        float p = e / sum;
        if (lane < 48) {
            ent -= p * logf(p + 1e-12f);
            a0 += p * c1[row];
            a1 += p * c2[row];
            a2 += p * s_c3[rl];
        }
    }
    #pragma unroll
    for (int off = 32; off; off >>= 1) ent += __shfl_xor(ent, off);
    if (lane == 0) entW[wv] = ent;
    if (lane < 48) { part[wv][lane][0] = a0; part[wv][lane][1] = a1; part[wv][lane][2] = a2; }
    __syncthreads();
    float* xp1 = ws + OFF_XP;
    if (tid < 144) {
        int j = tid / 3, col = tid % 3;
        float sp = 0.f;
        #pragma unroll
        for (int w = 0; w < 8; ++w) sp += part[w][j][col];
        atomicAdd(&xp1[j * 3 + col], sp);
    }
    if (tid == 0) {
        float sp = 0.f;
        #pragma unroll
        for (int w = 0; w < 8; ++w) sp += entW[w];
        atomicAdd(&xp1[144], sp);
    }
    // ---- last-block epilogue: pool stages 2..4 ----
    if (tid == 0) {
        __threadfence();
        int old = atomicAdd((int*)ws + OFF_XP + 152, 1);
        sh_last = (old == (int)gridDim.x - 1) ? 1 : 0;
    }
    __syncthreads();
    if (sh_last) {
        __shared__ float shXp[145];
        __shared__ float S2[48][12], xp2[12][3];
        __shared__ float S3[12][4], xp3[4][3];
        __shared__ float ent2, ent3;
        if (tid < 145) shXp[tid] = atomicAdd(&xp1[tid], 0.0f);  // coherent read
        if (tid == 0) { ent2 = 0.f; ent3 = 0.f; }
        __syncthreads();
        if (tid < 48) {
            float v[12], mx = -1e30f;
            #pragma unroll
            for (int j = 0; j < 12; j++) { v[j] = P2[tid * 12 + j]; mx = fmaxf(mx, v[j]); }
            float sm = 0.f;
            #pragma unroll
            for (int j = 0; j < 12; j++) { v[j] = expf(v[j] - mx); sm += v[j]; }
            float e = 0.f;
            #pragma unroll
            for (int j = 0; j < 12; j++) {
                float p = v[j] / sm; S2[tid][j] = p; e -= p * logf(p + 1e-12f);
            }
            atomicAdd(&ent2, e);
        }
        __syncthreads();
        if (tid < 36) {
            int j = tid / 3, col = tid % 3;
            float sm = 0.f;
            for (int i = 0; i < 48; i++) sm += S2[i][j] * shXp[i * 3 + col];
            xp2[j][col] = sm;
        }
        __syncthreads();
        if (tid < 12) {
            float v[4], mx = -1e30f;
            #pragma unroll
            for (int j = 0; j < 4; j++) { v[j] = P3[tid * 4 + j]; mx = fmaxf(mx, v[j]); }
            float sm = 0.f;
            #pragma unroll
            for (int j = 0; j < 4; j++) { v[j] = expf(v[j] - mx); sm += v[j]; }
            float e = 0.f;
            #pragma unroll
            for (int j = 0; j < 4; j++) {
                float p = v[j] / sm; S3[tid][j] = p; e -= p * logf(p + 1e-12f);
            }
            atomicAdd(&ent3, e);
        }
        __syncthreads();
        if (tid < 12) {
            int j = tid / 3, col = tid % 3;
            float sm = 0.f;
            for (int i = 0; i < 12; i++) sm += S3[i][j] * xp2[i][col];
            xp3[j][col] = sm;
        }
        __syncthreads();
        if (tid == 0) {
            float o0 = 0.f, o1 = 0.f, o2 = 0.f;
            for (int i = 0; i < 4; i++) {
                o0 += xp3[i][0]; o1 += xp3[i][1]; o2 += xp3[i][2];
            }
            // stage-4: width-1 softmax -> p==1, entropy==0 in fp32
            float reg = shXp[144] / (float)NN + ent2 / 48.f + ent3 / 12.f;
            out[0] = o0; out[1] = o1; out[2] = o2; out[3] = reg;
        }
    }
}

extern "C" void kernel_launch(void* const* d_in, const int* in_sizes, int n_in,
                              void* d_out, int out_size, void* d_ws, size_t ws_size,
                              hipStream_t stream) {
    const float* x  = (const float*)d_in[0];
    const int*   ei = (const int*)d_in[1];
    const float* ea = (const float*)d_in[2];
    // d_in[3] = adj — unused by the reference.
    const float* W1 = (const float*)d_in[4];
    const float* b1 = (const float*)d_in[5];
    const float* W2 = (const float*)d_in[6];
    const float* b2 = (const float*)d_in[7];
    const float* P1 = (const float*)d_in[8];
    const float* P2 = (const float*)d_in[9];
    const float* P3 = (const float*)d_in[10];
    // d_in[11] = P4 — width-1 softmax, handled analytically.
    const int* src = ei;
    const int* dst = ei + EE;
    float* ws  = (float*)d_ws;
    float* out = (float*)d_out;

    k1_deg_xw<<<256, NTHR, 0, stream>>>(dst, ea, x, W1, ws);
    k2_dinv<<<RB, NTHR, 0, stream>>>(ws);
    k_scat<<<SB, NTHR, 0, stream>>>(src, dst, ea, ws + OFF_U0, ws);
    k_red_conv<<<RB, NTHR, 0, stream>>>(ws + OFF_XW, nullptr, b1,
                                        ws + OFF_C1, ws + OFF_U1, ws);
    k_scat<<<SB, NTHR, 0, stream>>>(src, dst, ea, ws + OFF_U1, ws);
    k_red_conv<<<RB, NTHR, 0, stream>>>(ws + OFF_C1, W2, b2,
                                        ws + OFF_C2, ws + OFF_U2, ws);
    k_scat<<<SB, NTHR, 0, stream>>>(src, dst, ea, ws + OFF_U2, ws);
    k8_final<<<RB, NTHR, 0, stream>>>(ws + OFF_C2, W2, b2,
                                      ws + OFF_C1, ws + OFF_C2,
                                      P1, P2, P3, ws, out);
}